// Round 11
// baseline (550.010 us; speedup 1.0000x reference)
//
#include <hip/hip_runtime.h>

#define NB 16384
#define ND 512
#define NH 128
#define NHH 256
#define NG 18

typedef short s8v __attribute__((ext_vector_type(8)));
typedef __bf16 bf8v __attribute__((ext_vector_type(8)));
typedef float f16v __attribute__((ext_vector_type(16)));
typedef unsigned int u4v __attribute__((ext_vector_type(4)));

static __device__ __forceinline__ unsigned short f2bf(float f) {
  unsigned int u = __builtin_bit_cast(unsigned int, f);
  u += 0x7FFFu + ((u >> 16) & 1u);
  return (unsigned short)(u >> 16);
}

static __device__ __forceinline__ unsigned pk2(float a, float b) {
  return (unsigned)f2bf(a) | ((unsigned)f2bf(b) << 16);
}

static __device__ __forceinline__ f16v mfma32(s8v a, s8v b, f16v c) {
  return __builtin_amdgcn_mfma_f32_32x32x16_bf16(
      __builtin_bit_cast(bf8v, a), __builtin_bit_cast(bf8v, b), c, 0, 0, 0);
}

static __device__ __forceinline__ f16v zf16() {
  f16v v;
#pragma unroll
  for (int i = 0; i < 16; ++i) v[i] = 0.f;
  return v;
}

// per-ks compile-time swizzle XOR for fragment-linear H1/H2 reads
#define KM(ks) (((((ks) & 1) << 5)) | ((((ks) >> 1) & 1) << 6))

// pack W [G][K][N] f32 -> B-fragment-linear bf16 for mfma_32x32x16
__global__ __launch_bounds__(256) void k_pack(const float* __restrict__ in,
                                              unsigned short* __restrict__ out,
                                              int K, int N) {
  const int g = blockIdx.y;
  const int c = blockIdx.x * 256 + threadIdx.x;
  const int nk = K >> 4;
  const int l = c & 63;
  const int t = c >> 6;
  const int nt = t / nk;
  const int ks = t - nt * nk;
  const int k0 = (ks << 4) + ((l >> 5) << 3);
  const int col = (nt << 5) + (l & 31);
  const float* ip = in + (size_t)g * K * N + (size_t)k0 * N + col;
  u4v pk;
#pragma unroll
  for (int j = 0; j < 4; ++j)
    pk[j] = pk2(ip[(size_t)(2 * j) * N], ip[(size_t)(2 * j + 1) * N]);
  *(u4v*)(out + (size_t)g * K * N + ((size_t)c << 3)) = pk;
}

// pack Wa [512][18] -> fragment stream [32 ks][64 lane][8], cols >= 18 zeroed
__global__ __launch_bounds__(256) void k_packa(const float* __restrict__ wa,
                                               unsigned short* __restrict__ wap) {
  const int t = blockIdx.x * 256 + threadIdx.x;  // 0..2047
  const int ks = t >> 6, l = t & 63;
  const int col = l & 31;
  const int k0 = (ks << 4) + ((l >> 5) << 3);
  u4v pk;
  if (col < 18) {
    const float* ip = wa + (size_t)k0 * NG + col;
#pragma unroll
    for (int j = 0; j < 4; ++j)
      pk[j] = pk2(ip[(size_t)(2 * j) * NG], ip[(size_t)(2 * j + 1) * NG]);
  } else {
    pk[0] = pk[1] = pk[2] = pk[3] = 0u;
  }
  *(u4v*)(wap + ((size_t)t << 3)) = pk;
}

// fused attn + experts + aggregation. 1 block = 32 rows, 8 waves, 2 blocks/CU.
__global__ __launch_bounds__(512, 4) void k_main(
    const float* __restrict__ X,              // [B][512] f32
    const float* __restrict__ GV,             // [B][18]
    const unsigned short* __restrict__ w1p,   // packed [18][512x256]
    const unsigned short* __restrict__ w2p,   // packed [18][256x128]
    const unsigned short* __restrict__ w3p,   // packed [18][128x128]
    const unsigned short* __restrict__ w4p,   // packed [640x512]
    const unsigned short* __restrict__ wap,   // packed Wa [512x32]
    const float* __restrict__ b1, const float* __restrict__ b2,
    const float* __restrict__ b3, const float* __restrict__ bagg,
    const float* __restrict__ ba,
    float* __restrict__ out) {
  __shared__ __align__(16) char smem[64128];
  char* const XT = smem;                      // [32 ks][1024] = 32KB (linear)
  char* const H1 = smem + 32768;              // [16 ks][1024] = 16KB (swz)
  char* const H2 = smem + 49152;              // [8 ks][1024]  = 8KB  (swz)
  float* const Lsm = (float*)(smem + 57344);  // [32][33] f32
  float* const WL = (float*)(smem + 61568);   // [32][20] f32

  const int tid = threadIdx.x;
  const int row0 = blockIdx.x << 5;
  const int wid = tid >> 6, lane = tid & 63;
  const int l31 = lane & 31, lh = lane >> 5;
  const int lb = (lane << 4) ^ (lh << 4);     // swizzled read lane-base

  // ---- stage XT (f32 -> bf16) in fragment-linear order
#pragma unroll
  for (int i = 0; i < 4; ++i) {
    int ck = (i << 9) + tid;                  // chunk 0..2047
    int ks = ck >> 6, l = ck & 63;
    int grow = row0 + (l & 31);
    int c8 = (ks << 1) + (l >> 5);
    const float* xp = X + ((size_t)grow << 9) + (c8 << 3);
    float4 xa = *(const float4*)xp;
    float4 xc = *(const float4*)(xp + 4);
    u4v p;
    p[0] = pk2(xa.x, xa.y); p[1] = pk2(xa.z, xa.w);
    p[2] = pk2(xc.x, xc.y); p[3] = pk2(xc.z, xc.w);
    *(u4v*)(XT + (ck << 4)) = p;
  }

  // GEMM1 per-wave B base (col-tile = wid) and depth-8 queue prefetch (g=0)
  const unsigned short* const bp1 = w1p + (wid << 14) + (lane << 3);
  s8v bq[8];
#pragma unroll
  for (int i = 0; i < 8; ++i) bq[i] = *(const s8v*)(bp1 + (i << 9));

  __syncthreads();

  // ---- attention logits (wave 0 only): L = X @ Wa + ba via MFMA
  if (wid == 0) {
    f16v accL = zf16();
    const unsigned short* const bpa = wap + (lane << 3);
#pragma unroll
    for (int ks = 0; ks < 32; ++ks) {
      s8v a = *(const s8v*)(XT + (ks << 10) + (lane << 4));
      s8v b = *(const s8v*)(bpa + (ks << 9));
      accL = mfma32(a, b, accL);
    }
    const float bav = (l31 < NG) ? ba[l31] : 0.f;
#pragma unroll
    for (int r = 0; r < 16; ++r) {
      const int rl = (r & 3) + ((r >> 2) << 3) + (lh << 2);
      Lsm[rl * 33 + l31] = accL[r] + bav;
    }
  }

  // per-lane swizzled write base (cols gc1; H2 written only by wid<4)
  const int gc1 = (wid << 5) + l31;
  const int cb1 = ((gc1 >> 4) << 10) + (((gc1 >> 3) & 1) << 9) + ((gc1 & 7) << 1);
  const int m1 = (((cb1 >> 9) & 1) << 4) | (((cb1 >> 10) & 1) << 5) |
                 (((cb1 >> 11) & 1) << 6);

  const unsigned short* const bp2 = w2p + (wid << 13) + (lane << 3);   // wid<4
  const unsigned short* const bp3 = w3p + (wid << 12) + (lane << 3);   // wid<4
  const unsigned short* const bp4a = w4p + (size_t)wid * 20480 + (lane << 3);
  const unsigned short* const bp4b = w4p + (size_t)(wid + 8) * 20480 + (lane << 3);

  f16v racc = zf16();
  bool smdone = false;

  for (int g = 0; g < NG; ++g) {
    const unsigned short* const bp1g = bp1 + (size_t)g * 131072;
    // ---------- GEMM1: h1 = relu(X @ W1[g] + b1[g])  [32,256] ----------
    f16v acc10 = zf16(), acc11 = zf16();
#pragma unroll
    for (int ks = 0; ks < 32; ++ks) {
      s8v bn;
      const bool havenext = (ks < 24) || (g + 1 < NG);
      if (havenext) {
        size_t off = (ks < 24) ? (size_t)((ks + 8) << 9)
                               : (size_t)131072 + ((ks - 24) << 9);
        bn = *(const s8v*)(bp1g + off);
      }
      s8v a = *(const s8v*)(XT + (ks << 10) + (lane << 4));
      if (ks & 1) acc11 = mfma32(a, bq[ks & 7], acc11);
      else        acc10 = mfma32(a, bq[ks & 7], acc10);
      if (havenext) bq[ks & 7] = bn;
    }
    {
      const float bv1 = b1[(g << 8) + gc1];
#pragma unroll
      for (int r = 0; r < 16; ++r) {
        const int rl = (r & 3) + ((r >> 2) << 3) + (lh << 2);
        float v = fmaxf(acc10[r] + acc11[r] + bv1, 0.f);
        *(unsigned short*)(H1 + ((cb1 + (rl << 4)) ^ m1)) = f2bf(v);
      }
    }
    // hoist GEMM2 B-fragments + bias across the barrier (waves 0-3 only)
    s8v b2f[16];
    float bv2;
    if (wid < 4) {
      const unsigned short* const bp2g = bp2 + ((size_t)g << 15);
#pragma unroll
      for (int ks = 0; ks < 16; ++ks) b2f[ks] = *(const s8v*)(bp2g + (ks << 9));
      bv2 = b2[(g << 7) + gc1];
    }
    __syncthreads();

    // softmax (once, after logits are visible): 4 rows per wave
    if (!smdone) {
      if (lane < 4) {
        const int row = (wid << 2) + lane;
        float lg[NG], mx = -3.4e38f;
#pragma unroll
        for (int q = 0; q < NG; ++q) { lg[q] = Lsm[row * 33 + q]; mx = fmaxf(mx, lg[q]); }
        float s = 0.f;
#pragma unroll
        for (int q = 0; q < NG; ++q) { lg[q] = expf(lg[q] - mx); s += lg[q]; }
        const float inv = 1.f / s;
#pragma unroll
        for (int q = 0; q < NG; ++q) {
          float gv = GV[(size_t)(row0 + row) * NG + q];
          WL[row * 20 + q] = gv > 0.f ? lg[q] * inv * gv : 0.f;
        }
      }
      smdone = true;
    }

    if (wid < 4) {
      // ---------- GEMM2: h2 = relu(h1 @ W2[g] + b2[g])  [32,128] ----------
      f16v acc2a = zf16(), acc2b = zf16();
#pragma unroll
      for (int ks = 0; ks < 16; ks += 2) {
        s8v a0 = *(const s8v*)(H1 + (((ks << 10) + lb) ^ KM(ks)));
        s8v a1 = *(const s8v*)(H1 + ((((ks + 1) << 10) + lb) ^ KM(ks + 1)));
        acc2a = mfma32(a0, b2f[ks], acc2a);
        acc2b = mfma32(a1, b2f[ks + 1], acc2b);
      }
#pragma unroll
      for (int r = 0; r < 16; ++r) {
        const int rl = (r & 3) + ((r >> 2) << 3) + (lh << 2);
        float v = fmaxf(acc2a[r] + acc2b[r] + bv2, 0.f);
        *(unsigned short*)(H2 + ((cb1 + (rl << 4)) ^ m1)) = f2bf(v);
      }
    }
    // hoist GEMM3 B-fragments + bias (waves 0-3 only)
    s8v b3f[8];
    float bv3;
    if (wid < 4) {
      const unsigned short* const bp3g = bp3 + ((size_t)g << 14);
#pragma unroll
      for (int ks = 0; ks < 8; ++ks) b3f[ks] = *(const s8v*)(bp3g + (ks << 9));
      bv3 = b3[(g << 7) + gc1];
    }
    __syncthreads();

    if (wid < 4) {
      // ---------- GEMM3: h3 = h2 @ W3[g] + b3[g]; racc += w*h3 ----------
      f16v acc3a = zf16(), acc3b = zf16();
#pragma unroll
      for (int ks = 0; ks < 8; ks += 2) {
        s8v a0 = *(const s8v*)(H2 + (((ks << 10) + lb) ^ KM(ks)));
        s8v a1 = *(const s8v*)(H2 + ((((ks + 1) << 10) + lb) ^ KM(ks + 1)));
        acc3a = mfma32(a0, b3f[ks], acc3a);
        acc3b = mfma32(a1, b3f[ks + 1], acc3b);
      }
#pragma unroll
      for (int r = 0; r < 16; ++r) {
        const int rl = (r & 3) + ((r >> 2) << 3) + (lh << 2);
        racc[r] += WL[rl * 20 + g] * (acc3a[r] + acc3b[r] + bv3);
      }
    }
  }

  // prefetch GEMM4 depth-4 dual queue (flies across the barriers)
  s8v bq4[4][2];
#pragma unroll
  for (int k = 0; k < 4; ++k) {
    bq4[k][0] = *(const s8v*)(bp4a + (k << 9));
    bq4[k][1] = *(const s8v*)(bp4b + (k << 9));
  }
  __syncthreads();  // all GEMM3 H2 reads done
  if (wid < 4) {
#pragma unroll
    for (int r = 0; r < 16; ++r) {
      const int rl = (r & 3) + ((r >> 2) << 3) + (lh << 2);
      *(unsigned short*)(H2 + ((cb1 + (rl << 4)) ^ m1)) = f2bf(racc[r]);
    }
  }
  __syncthreads();

  // ---------- GEMM4: out = relu([X | ref] @ Wagg + bagg)  [32,512] ----------
  f16v acc4a = zf16(), acc4b = zf16();
#pragma unroll
  for (int ks = 0; ks < 40; ++ks) {
    s8v bn0, bn1;
    if (ks < 36) {
      bn0 = *(const s8v*)(bp4a + ((ks + 4) << 9));
      bn1 = *(const s8v*)(bp4b + ((ks + 4) << 9));
    }
    s8v a;
    if (ks < 32) {
      a = *(const s8v*)(XT + (ks << 10) + (lane << 4));
    } else {
      const int hk = ks - 32;
      a = *(const s8v*)(H2 + (((hk << 10) + lb) ^ KM(hk)));
    }
    acc4a = mfma32(a, bq4[ks & 3][0], acc4a);
    acc4b = mfma32(a, bq4[ks & 3][1], acc4b);
    if (ks < 36) { bq4[ks & 3][0] = bn0; bq4[ks & 3][1] = bn1; }
  }
  {
    const float bv4a = bagg[gc1];
    const float bv4b = bagg[gc1 + 256];
#pragma unroll
    for (int r = 0; r < 16; ++r) {
      const int rl = (r & 3) + ((r >> 2) << 3) + (lh << 2);
      const size_t rbase = (size_t)(row0 + rl) << 9;
      out[rbase + gc1] = fmaxf(acc4a[r] + bv4a, 0.f);
      out[rbase + gc1 + 256] = fmaxf(acc4b[r] + bv4b, 0.f);
    }
  }
}

// ---------------- workspace layout (bytes) ----------------
#define OFF_W1P   0u          // packed W1   : 4718592
#define OFF_W2P   4718592u    // packed W2   : 1179648
#define OFF_W3P   5898240u    // packed W3   : 589824
#define OFF_W4P   6488064u    // packed Wagg : 655360
#define OFF_WAP   7143424u    // packed Wa   : 32768   (end 7176192)

extern "C" void kernel_launch(void* const* d_in, const int* in_sizes, int n_in,
                              void* d_out, int out_size, void* d_ws, size_t ws_size,
                              hipStream_t stream) {
  const float* X    = (const float*)d_in[0];
  const float* GV   = (const float*)d_in[1];
  const float* W1   = (const float*)d_in[2];
  const float* b1   = (const float*)d_in[3];
  const float* W2   = (const float*)d_in[4];
  const float* b2   = (const float*)d_in[5];
  const float* W3   = (const float*)d_in[6];
  const float* b3   = (const float*)d_in[7];
  const float* Wa   = (const float*)d_in[8];
  const float* ba   = (const float*)d_in[9];
  const float* Wagg = (const float*)d_in[10];
  const float* bagg = (const float*)d_in[11];
  float* out = (float*)d_out;
  char* ws = (char*)d_ws;

  unsigned short* w1p = (unsigned short*)(ws + OFF_W1P);
  unsigned short* w2p = (unsigned short*)(ws + OFF_W2P);
  unsigned short* w3p = (unsigned short*)(ws + OFF_W3P);
  unsigned short* w4p = (unsigned short*)(ws + OFF_W4P);
  unsigned short* wap = (unsigned short*)(ws + OFF_WAP);

  k_pack<<<dim3(64, 18), 256, 0, stream>>>(W1, w1p, 512, 256);
  k_pack<<<dim3(16, 18), 256, 0, stream>>>(W2, w2p, 256, 128);
  k_pack<<<dim3(8, 18), 256, 0, stream>>>(W3, w3p, 128, 128);
  k_pack<<<dim3(160, 1), 256, 0, stream>>>(Wagg, w4p, 640, 512);
  k_packa<<<8, 256, 0, stream>>>(Wa, wap);
  k_main<<<512, 512, 0, stream>>>(X, GV, w1p, w2p, w3p, w4p, wap,
                                  b1, b2, b3, bagg, ba, out);
}

// Round 12
// 211.457 us; speedup vs baseline: 2.6010x; 2.6010x over previous
//
#include <hip/hip_runtime.h>

#define NB 16384
#define ND 512
#define NH 128
#define NHH 256
#define NG 18

typedef short s8v __attribute__((ext_vector_type(8)));
typedef __bf16 bf8v __attribute__((ext_vector_type(8)));
typedef float f16v __attribute__((ext_vector_type(16)));
typedef unsigned int u4v __attribute__((ext_vector_type(4)));

static __device__ __forceinline__ unsigned short f2bf(float f) {
  unsigned int u = __builtin_bit_cast(unsigned int, f);
  u += 0x7FFFu + ((u >> 16) & 1u);
  return (unsigned short)(u >> 16);
}

static __device__ __forceinline__ unsigned pk2(float a, float b) {
  return (unsigned)f2bf(a) | ((unsigned)f2bf(b) << 16);
}

static __device__ __forceinline__ f16v mfma32(s8v a, s8v b, f16v c) {
  return __builtin_amdgcn_mfma_f32_32x32x16_bf16(
      __builtin_bit_cast(bf8v, a), __builtin_bit_cast(bf8v, b), c, 0, 0, 0);
}

static __device__ __forceinline__ f16v zf16() {
  f16v v;
#pragma unroll
  for (int i = 0; i < 16; ++i) v[i] = 0.f;
  return v;
}

// per-ks compile-time swizzle XOR for fragment-linear H1/H2 reads
#define KM(ks) (((((ks) & 1) << 5)) | ((((ks) >> 1) & 1) << 6))

// pack W [G][K][N] f32 -> B-fragment-linear bf16 for mfma_32x32x16
__global__ __launch_bounds__(256) void k_pack(const float* __restrict__ in,
                                              unsigned short* __restrict__ out,
                                              int K, int N) {
  const int g = blockIdx.y;
  const int c = blockIdx.x * 256 + threadIdx.x;
  const int nk = K >> 4;
  const int l = c & 63;
  const int t = c >> 6;
  const int nt = t / nk;
  const int ks = t - nt * nk;
  const int k0 = (ks << 4) + ((l >> 5) << 3);
  const int col = (nt << 5) + (l & 31);
  const float* ip = in + (size_t)g * K * N + (size_t)k0 * N + col;
  u4v pk;
#pragma unroll
  for (int j = 0; j < 4; ++j)
    pk[j] = pk2(ip[(size_t)(2 * j) * N], ip[(size_t)(2 * j + 1) * N]);
  *(u4v*)(out + (size_t)g * K * N + ((size_t)c << 3)) = pk;
}

// pack Wa [512][18] -> fragment stream [32 ks][64 lane][8], cols >= 18 zeroed
__global__ __launch_bounds__(256) void k_packa(const float* __restrict__ wa,
                                               unsigned short* __restrict__ wap) {
  const int t = blockIdx.x * 256 + threadIdx.x;  // 0..2047
  const int ks = t >> 6, l = t & 63;
  const int col = l & 31;
  const int k0 = (ks << 4) + ((l >> 5) << 3);
  u4v pk;
  if (col < 18) {
    const float* ip = wa + (size_t)k0 * NG + col;
#pragma unroll
    for (int j = 0; j < 4; ++j)
      pk[j] = pk2(ip[(size_t)(2 * j) * NG], ip[(size_t)(2 * j + 1) * NG]);
  } else {
    pk[0] = pk[1] = pk[2] = pk[3] = 0u;
  }
  *(u4v*)(wap + ((size_t)t << 3)) = pk;
}

// fused attn + experts + aggregation. 1 block = 32 rows, 8 waves.
// Spill-proof register plan (~112 live peak) so compiler lands <=128 VGPR
// -> HW fits 2 blocks/CU (LDS 64128 x2 <= 160K, 16 waves x 128 = 2048 VGPR file).
__global__ __launch_bounds__(512, 1) void k_main(
    const float* __restrict__ X,              // [B][512] f32
    const float* __restrict__ GV,             // [B][18]
    const unsigned short* __restrict__ w1p,   // packed [18][512x256]
    const unsigned short* __restrict__ w2p,   // packed [18][256x128]
    const unsigned short* __restrict__ w3p,   // packed [18][128x128]
    const unsigned short* __restrict__ w4p,   // packed [640x512]
    const unsigned short* __restrict__ wap,   // packed Wa [512x32]
    const float* __restrict__ b1, const float* __restrict__ b2,
    const float* __restrict__ b3, const float* __restrict__ bagg,
    const float* __restrict__ ba,
    float* __restrict__ out) {
  __shared__ __align__(16) char smem[64128];
  char* const XT = smem;                      // [32 ks][1024] = 32KB (linear)
  char* const H1 = smem + 32768;              // [16 ks][1024] = 16KB (swz)
  char* const H2 = smem + 49152;              // [8 ks][1024]  = 8KB  (swz)
  float* const Lsm = (float*)(smem + 57344);  // [32][33] f32
  float* const WL = (float*)(smem + 61568);   // [32][20] f32

  const int tid = threadIdx.x;
  const int row0 = blockIdx.x << 5;
  const int wid = tid >> 6, lane = tid & 63;
  const int l31 = lane & 31, lh = lane >> 5;
  const int lb = (lane << 4) ^ (lh << 4);     // swizzled read lane-base

  // ---- stage XT (f32 -> bf16) in fragment-linear order
#pragma unroll
  for (int i = 0; i < 4; ++i) {
    int ck = (i << 9) + tid;                  // chunk 0..2047
    int ks = ck >> 6, l = ck & 63;
    int grow = row0 + (l & 31);
    int c8 = (ks << 1) + (l >> 5);
    const float* xp = X + ((size_t)grow << 9) + (c8 << 3);
    float4 xa = *(const float4*)xp;
    float4 xc = *(const float4*)(xp + 4);
    u4v p;
    p[0] = pk2(xa.x, xa.y); p[1] = pk2(xa.z, xa.w);
    p[2] = pk2(xc.x, xc.y); p[3] = pk2(xc.z, xc.w);
    *(u4v*)(XT + (ck << 4)) = p;
  }

  // GEMM1 per-wave B base (col-tile = wid), depth-4 queue prefetch (g=0)
  const unsigned short* const bp1 = w1p + (wid << 14) + (lane << 3);
  s8v bq[4];
#pragma unroll
  for (int i = 0; i < 4; ++i) bq[i] = *(const s8v*)(bp1 + (i << 9));

  __syncthreads();

  // ---- attention logits (wave 0 only): L = X @ Wa + ba via MFMA
  if (wid == 0) {
    f16v accL = zf16();
    const unsigned short* const bpa = wap + (lane << 3);
#pragma unroll
    for (int ks = 0; ks < 32; ++ks) {
      s8v a = *(const s8v*)(XT + (ks << 10) + (lane << 4));
      s8v b = *(const s8v*)(bpa + (ks << 9));
      accL = mfma32(a, b, accL);
    }
    const float bav = (l31 < NG) ? ba[l31] : 0.f;
#pragma unroll
    for (int r = 0; r < 16; ++r) {
      const int rl = (r & 3) + ((r >> 2) << 3) + (lh << 2);
      Lsm[rl * 33 + l31] = accL[r] + bav;
    }
  }

  // per-lane swizzled write base (cols gc1; H2 written only by wid<4)
  const int gc1 = (wid << 5) + l31;
  const int cb1 = ((gc1 >> 4) << 10) + (((gc1 >> 3) & 1) << 9) + ((gc1 & 7) << 1);
  const int m1 = (((cb1 >> 9) & 1) << 4) | (((cb1 >> 10) & 1) << 5) |
                 (((cb1 >> 11) & 1) << 6);

  const unsigned short* const bp2 = w2p + (wid << 13) + (lane << 3);   // wid<4
  const unsigned short* const bp3 = w3p + (wid << 12) + (lane << 3);   // wid<4
  const unsigned short* const bp4a = w4p + (size_t)wid * 20480 + (lane << 3);
  const unsigned short* const bp4b = w4p + (size_t)(wid + 8) * 20480 + (lane << 3);

  f16v racc = zf16();

  for (int g = 0; g < NG; ++g) {
    const unsigned short* const bp1g = bp1 + (size_t)g * 131072;
    // ---------- GEMM1: h1 = relu(X @ W1[g] + b1[g])  [32,256] ----------
    f16v acc10 = zf16(), acc11 = zf16();
#pragma unroll
    for (int ks = 0; ks < 32; ++ks) {
      s8v bn;
      const bool havenext = (ks < 28) || (g + 1 < NG);
      if (havenext) {
        size_t off = (ks < 28) ? (size_t)((ks + 4) << 9)
                               : (size_t)131072 + ((ks - 28) << 9);
        bn = *(const s8v*)(bp1g + off);
      }
      s8v a = *(const s8v*)(XT + (ks << 10) + (lane << 4));
      if (ks & 1) acc11 = mfma32(a, bq[ks & 3], acc11);
      else        acc10 = mfma32(a, bq[ks & 3], acc10);
      if (havenext) bq[ks & 3] = bn;
    }
    {
      const float bv1 = b1[(g << 8) + gc1];
#pragma unroll
      for (int r = 0; r < 16; ++r) {
        const int rl = (r & 3) + ((r >> 2) << 3) + (lh << 2);
        float v = fmaxf(acc10[r] + acc11[r] + bv1, 0.f);
        *(unsigned short*)(H1 + ((cb1 + (rl << 4)) ^ m1)) = f2bf(v);
      }
    }
    // hoist GEMM2 B first half (8 frags) + bias across the barrier (wid<4)
    s8v q2[8];
    float bv2;
    const unsigned short* const bp2g = bp2 + ((size_t)g << 15);
    if (wid < 4) {
#pragma unroll
      for (int i = 0; i < 8; ++i) q2[i] = *(const s8v*)(bp2g + (i << 9));
      bv2 = b2[(g << 7) + gc1];
    }
    __syncthreads();

    // softmax (once, after logits visible): 4 rows per wave
    if (g == 0) {
      if (lane < 4) {
        const int row = (wid << 2) + lane;
        float lg[NG], mx = -3.4e38f;
#pragma unroll
        for (int q = 0; q < NG; ++q) { lg[q] = Lsm[row * 33 + q]; mx = fmaxf(mx, lg[q]); }
        float s = 0.f;
#pragma unroll
        for (int q = 0; q < NG; ++q) { lg[q] = expf(lg[q] - mx); s += lg[q]; }
        const float inv = 1.f / s;
#pragma unroll
        for (int q = 0; q < NG; ++q) {
          float gv = GV[(size_t)(row0 + row) * NG + q];
          WL[row * 20 + q] = gv > 0.f ? lg[q] * inv * gv : 0.f;
        }
      }
    }

    if (wid < 4) {
      // ---------- GEMM2: h2 = relu(h1 @ W2[g] + b2[g])  [32,128] ----------
      // rolling queue: slot i refilled with frag i+8 after consumption;
      // refill latency covered by the co-resident block.
      f16v acc2a = zf16(), acc2b = zf16();
#pragma unroll
      for (int i = 0; i < 16; ++i) {
        s8v a = *(const s8v*)(H1 + (((i << 10) + lb) ^ KM(i)));
        s8v cur = q2[i & 7];
        if (i < 8) q2[i & 7] = *(const s8v*)(bp2g + ((i + 8) << 9));
        if (i & 1) acc2b = mfma32(a, cur, acc2b);
        else       acc2a = mfma32(a, cur, acc2a);
      }
#pragma unroll
      for (int r = 0; r < 16; ++r) {
        const int rl = (r & 3) + ((r >> 2) << 3) + (lh << 2);
        float v = fmaxf(acc2a[r] + acc2b[r] + bv2, 0.f);
        *(unsigned short*)(H2 + ((cb1 + (rl << 4)) ^ m1)) = f2bf(v);
      }
    }
    // hoist GEMM3 B-fragments (8 total) + bias (wid<4)
    s8v b3f[8];
    float bv3;
    if (wid < 4) {
      const unsigned short* const bp3g = bp3 + ((size_t)g << 14);
#pragma unroll
      for (int ks = 0; ks < 8; ++ks) b3f[ks] = *(const s8v*)(bp3g + (ks << 9));
      bv3 = b3[(g << 7) + gc1];
    }
    __syncthreads();

    if (wid < 4) {
      // ---------- GEMM3: h3 = h2 @ W3[g] + b3[g]; racc += w*h3 ----------
      f16v acc3a = zf16(), acc3b = zf16();
#pragma unroll
      for (int ks = 0; ks < 8; ks += 2) {
        s8v a0 = *(const s8v*)(H2 + (((ks << 10) + lb) ^ KM(ks)));
        s8v a1 = *(const s8v*)(H2 + ((((ks + 1) << 10) + lb) ^ KM(ks + 1)));
        acc3a = mfma32(a0, b3f[ks], acc3a);
        acc3b = mfma32(a1, b3f[ks + 1], acc3b);
      }
#pragma unroll
      for (int r = 0; r < 16; ++r) {
        const int rl = (r & 3) + ((r >> 2) << 3) + (lh << 2);
        racc[r] += WL[rl * 20 + g] * (acc3a[r] + acc3b[r] + bv3);
      }
    }
  }

  // prefetch GEMM4 depth-4 dual queue (flies across the barriers)
  s8v bq4[4][2];
#pragma unroll
  for (int k = 0; k < 4; ++k) {
    bq4[k][0] = *(const s8v*)(bp4a + (k << 9));
    bq4[k][1] = *(const s8v*)(bp4b + (k << 9));
  }
  __syncthreads();  // all GEMM3 H2 reads done
  if (wid < 4) {
#pragma unroll
    for (int r = 0; r < 16; ++r) {
      const int rl = (r & 3) + ((r >> 2) << 3) + (lh << 2);
      *(unsigned short*)(H2 + ((cb1 + (rl << 4)) ^ m1)) = f2bf(racc[r]);
    }
  }
  __syncthreads();

  // ---------- GEMM4: out = relu([X | ref] @ Wagg + bagg)  [32,512] ----------
  f16v acc4a = zf16(), acc4b = zf16();
#pragma unroll
  for (int ks = 0; ks < 40; ++ks) {
    s8v bn0, bn1;
    if (ks < 36) {
      bn0 = *(const s8v*)(bp4a + ((ks + 4) << 9));
      bn1 = *(const s8v*)(bp4b + ((ks + 4) << 9));
    }
    s8v a;
    if (ks < 32) {
      a = *(const s8v*)(XT + (ks << 10) + (lane << 4));
    } else {
      const int hk = ks - 32;
      a = *(const s8v*)(H2 + (((hk << 10) + lb) ^ KM(hk)));
    }
    acc4a = mfma32(a, bq4[ks & 3][0], acc4a);
    acc4b = mfma32(a, bq4[ks & 3][1], acc4b);
    if (ks < 36) { bq4[ks & 3][0] = bn0; bq4[ks & 3][1] = bn1; }
  }
  {
    const float bv4a = bagg[gc1];
    const float bv4b = bagg[gc1 + 256];
#pragma unroll
    for (int r = 0; r < 16; ++r) {
      const int rl = (r & 3) + ((r >> 2) << 3) + (lh << 2);
      const size_t rbase = (size_t)(row0 + rl) << 9;
      out[rbase + gc1] = fmaxf(acc4a[r] + bv4a, 0.f);
      out[rbase + gc1 + 256] = fmaxf(acc4b[r] + bv4b, 0.f);
    }
  }
}

// ---------------- workspace layout (bytes) ----------------
#define OFF_W1P   0u          // packed W1   : 4718592
#define OFF_W2P   4718592u    // packed W2   : 1179648
#define OFF_W3P   5898240u    // packed W3   : 589824
#define OFF_W4P   6488064u    // packed Wagg : 655360
#define OFF_WAP   7143424u    // packed Wa   : 32768   (end 7176192)

extern "C" void kernel_launch(void* const* d_in, const int* in_sizes, int n_in,
                              void* d_out, int out_size, void* d_ws, size_t ws_size,
                              hipStream_t stream) {
  const float* X    = (const float*)d_in[0];
  const float* GV   = (const float*)d_in[1];
  const float* W1   = (const float*)d_in[2];
  const float* b1   = (const float*)d_in[3];
  const float* W2   = (const float*)d_in[4];
  const float* b2   = (const float*)d_in[5];
  const float* W3   = (const float*)d_in[6];
  const float* b3   = (const float*)d_in[7];
  const float* Wa   = (const float*)d_in[8];
  const float* ba   = (const float*)d_in[9];
  const float* Wagg = (const float*)d_in[10];
  const float* bagg = (const float*)d_in[11];
  float* out = (float*)d_out;
  char* ws = (char*)d_ws;

  unsigned short* w1p = (unsigned short*)(ws + OFF_W1P);
  unsigned short* w2p = (unsigned short*)(ws + OFF_W2P);
  unsigned short* w3p = (unsigned short*)(ws + OFF_W3P);
  unsigned short* w4p = (unsigned short*)(ws + OFF_W4P);
  unsigned short* wap = (unsigned short*)(ws + OFF_WAP);

  k_pack<<<dim3(64, 18), 256, 0, stream>>>(W1, w1p, 512, 256);
  k_pack<<<dim3(16, 18), 256, 0, stream>>>(W2, w2p, 256, 128);
  k_pack<<<dim3(8, 18), 256, 0, stream>>>(W3, w3p, 128, 128);
  k_pack<<<dim3(160, 1), 256, 0, stream>>>(Wagg, w4p, 640, 512);
  k_packa<<<8, 256, 0, stream>>>(Wa, wap);
  k_main<<<512, 512, 0, stream>>>(X, GV, w1p, w2p, w3p, w4p, wap,
                                  b1, b2, b3, bagg, ba, out);
}

// Round 13
// 159.638 us; speedup vs baseline: 3.4454x; 1.3246x over previous
//
#include <hip/hip_runtime.h>

#define NB 16384
#define ND 512
#define NH 128
#define NHH 256
#define NG 18

typedef short s8v __attribute__((ext_vector_type(8)));
typedef __bf16 bf8v __attribute__((ext_vector_type(8)));
typedef float f16v __attribute__((ext_vector_type(16)));
typedef unsigned int u4v __attribute__((ext_vector_type(4)));

static __device__ __forceinline__ unsigned short f2bf(float f) {
  unsigned int u = __builtin_bit_cast(unsigned int, f);
  u += 0x7FFFu + ((u >> 16) & 1u);
  return (unsigned short)(u >> 16);
}

static __device__ __forceinline__ unsigned pk2(float a, float b) {
  return (unsigned)f2bf(a) | ((unsigned)f2bf(b) << 16);
}

static __device__ __forceinline__ f16v mfma32(s8v a, s8v b, f16v c) {
  return __builtin_amdgcn_mfma_f32_32x32x16_bf16(
      __builtin_bit_cast(bf8v, a), __builtin_bit_cast(bf8v, b), c, 0, 0, 0);
}

static __device__ __forceinline__ f16v zf16() {
  f16v v;
#pragma unroll
  for (int i = 0; i < 16; ++i) v[i] = 0.f;
  return v;
}

// per-ks compile-time swizzle XOR for fragment-linear H1/H2 reads
#define KM(ks) (((((ks) & 1) << 5)) | ((((ks) >> 1) & 1) << 6))

// pack W [G][K][N] f32 -> B-fragment-linear bf16 for mfma_32x32x16
__global__ __launch_bounds__(256) void k_pack(const float* __restrict__ in,
                                              unsigned short* __restrict__ out,
                                              int K, int N) {
  const int g = blockIdx.y;
  const int c = blockIdx.x * 256 + threadIdx.x;
  const int nk = K >> 4;
  const int l = c & 63;
  const int t = c >> 6;
  const int nt = t / nk;
  const int ks = t - nt * nk;
  const int k0 = (ks << 4) + ((l >> 5) << 3);
  const int col = (nt << 5) + (l & 31);
  const float* ip = in + (size_t)g * K * N + (size_t)k0 * N + col;
  u4v pk;
#pragma unroll
  for (int j = 0; j < 4; ++j)
    pk[j] = pk2(ip[(size_t)(2 * j) * N], ip[(size_t)(2 * j + 1) * N]);
  *(u4v*)(out + (size_t)g * K * N + ((size_t)c << 3)) = pk;
}

// pack Wa [512][18] -> fragment stream [32 ks][64 lane][8], cols >= 18 zeroed
__global__ __launch_bounds__(256) void k_packa(const float* __restrict__ wa,
                                               unsigned short* __restrict__ wap) {
  const int t = blockIdx.x * 256 + threadIdx.x;  // 0..2047
  const int ks = t >> 6, l = t & 63;
  const int col = l & 31;
  const int k0 = (ks << 4) + ((l >> 5) << 3);
  u4v pk;
  if (col < 18) {
    const float* ip = wa + (size_t)k0 * NG + col;
#pragma unroll
    for (int j = 0; j < 4; ++j)
      pk[j] = pk2(ip[(size_t)(2 * j) * NG], ip[(size_t)(2 * j + 1) * NG]);
  } else {
    pk[0] = pk[1] = pk[2] = pk[3] = 0u;
  }
  *(u4v*)(wap + ((size_t)t << 3)) = pk;
}

// fused attn + experts + aggregation. 1 block = 64 rows, 8 waves, mfma 32x32x16.
// Cross-genre pipeline: GEMM1(g+1) interleaved into GEMM2(g)/GEMM3(g) phases.
__global__ __launch_bounds__(512, 1) void k_main(
    const float* __restrict__ X,              // [B][512] f32
    const float* __restrict__ GV,             // [B][18]
    const unsigned short* __restrict__ w1p,   // packed [18][512x256]
    const unsigned short* __restrict__ w2p,   // packed [18][256x128]
    const unsigned short* __restrict__ w3p,   // packed [18][128x128]
    const unsigned short* __restrict__ w4p,   // packed [640x512]
    const unsigned short* __restrict__ wap,   // packed Wa [512x32]
    const float* __restrict__ b1, const float* __restrict__ b2,
    const float* __restrict__ b3, const float* __restrict__ bagg,
    const float* __restrict__ ba,
    float* __restrict__ out) {
  __shared__ __align__(16) char smem[128256];
  char* const XT = smem;                      // [2][32][1024] = 64KB (linear)
  char* const H1 = smem + 65536;              // [2][16][1024] = 32KB (swz)
  char* const H2 = smem + 98304;              // [2][8][1024]  = 16KB (swz)
  float* const WL = (float*)(smem + 114688);  // [64][20] f32 (5120B)
  float* const Lsm = (float*)(smem + 119808); // [64][33] f32 (8448B)

  const int tid = threadIdx.x;
  const int row0 = blockIdx.x << 6;
  const int wid = tid >> 6, lane = tid & 63;
  const int l31 = lane & 31, lh = lane >> 5;
  const int lb = (lane << 4) ^ (lh << 4);     // swizzled read lane-base

  // ---- stage XT (f32 -> bf16) in fragment-linear order
#pragma unroll
  for (int i = 0; i < 8; ++i) {
    int ck = (i << 9) + tid;                  // chunk 0..4095
    int mt = ck >> 11, ks = (ck >> 6) & 31, l = ck & 63;
    int grow = row0 + (mt << 5) + (l & 31);
    int c8 = (ks << 1) + (l >> 5);
    const float* xp = X + ((size_t)grow << 9) + (c8 << 3);
    float4 xa = *(const float4*)xp;
    float4 xc = *(const float4*)(xp + 4);
    u4v p;
    p[0] = pk2(xa.x, xa.y); p[1] = pk2(xa.z, xa.w);
    p[2] = pk2(xc.x, xc.y); p[3] = pk2(xc.z, xc.w);
    *(u4v*)(XT + (ck << 4)) = p;
  }

  // GEMM1 per-wave B base (col-tile = wid); depth-4 queue, g=0 ks0..3
  const unsigned short* const bp1 = w1p + (wid << 14) + (lane << 3);
  s8v bq1[4];
#pragma unroll
  for (int i = 0; i < 4; ++i) bq1[i] = *(const s8v*)(bp1 + (i << 9));

  __syncthreads();

  // ---- attention logits: L = X @ Wa + ba via MFMA (waves 0,1)
  if (wid < 2) {
    f16v accL = zf16();
    const unsigned short* const bpa = wap + (lane << 3);
#pragma unroll
    for (int ks = 0; ks < 32; ++ks) {
      s8v a = *(const s8v*)(XT + (wid << 15) + (ks << 10) + (lane << 4));
      s8v b = *(const s8v*)(bpa + (ks << 9));
      accL = mfma32(a, b, accL);
    }
    const float bav = (l31 < NG) ? ba[l31] : 0.f;
#pragma unroll
    for (int r = 0; r < 16; ++r) {
      const int rl = (r & 3) + ((r >> 2) << 3) + (lh << 2);
      Lsm[((wid << 5) + rl) * 33 + l31] = accL[r] + bav;
    }
  }
  __syncthreads();

  // ---- softmax * genre mask -> WL (8 lanes per wave, one row each)
  if (lane < 8) {
    const int row = (wid << 3) + lane;
    float lg[NG], mx = -3.4e38f;
#pragma unroll
    for (int q = 0; q < NG; ++q) { lg[q] = Lsm[row * 33 + q]; mx = fmaxf(mx, lg[q]); }
    float s = 0.f;
#pragma unroll
    for (int q = 0; q < NG; ++q) { lg[q] = expf(lg[q] - mx); s += lg[q]; }
    const float inv = 1.f / s;
#pragma unroll
    for (int q = 0; q < NG; ++q) {
      float gv = GV[(size_t)(row0 + row) * NG + q];
      WL[row * 20 + q] = gv > 0.f ? lg[q] * inv * gv : 0.f;
    }
  }

  // ---- wave tile assignment
  const int nt2 = wid & 3, mt2 = wid >> 2;    // GEMM2/3 tile
  const unsigned short* const bp2 = w2p + (nt2 << 13) + (lane << 3);
  const unsigned short* const bp3 = w3p + (nt2 << 12) + (lane << 3);
  const unsigned short* const bp4a = w4p + (size_t)wid * 20480 + (lane << 3);
  const unsigned short* const bp4b = w4p + (size_t)(wid + 8) * 20480 + (lane << 3);

  // per-lane swizzled write bases (genre-invariant)
  const int gc1 = (wid << 5) + l31;           // GEMM1 col
  const int gc2 = (nt2 << 5) + l31;           // GEMM2/3 col
  const int cb1 = ((gc1 >> 4) << 10) + (((gc1 >> 3) & 1) << 9) + ((gc1 & 7) << 1);
  const int cb2 = ((gc2 >> 4) << 10) + (((gc2 >> 3) & 1) << 9) + ((gc2 & 7) << 1);
  const int m1 = (((cb1 >> 9) & 1) << 4) | (((cb1 >> 10) & 1) << 5) | (((cb1 >> 11) & 1) << 6);
  const int m2 = (((cb2 >> 9) & 1) << 4) | (((cb2 >> 10) & 1) << 5) | (((cb2 >> 11) & 1) << 6);

  f16v racc = zf16();
  s8v q2[8];
  float bv2;

  // ---- prologue: GEMM1(0) full (not pipelined)
  {
    f16v accA0 = zf16(), accA1 = zf16(), accB0 = zf16(), accB1 = zf16();
#pragma unroll
    for (int ks = 0; ks < 32; ++ks) {
      s8v bn;
      {
        size_t off = (ks < 28) ? (size_t)((ks + 4) << 9)
                               : (size_t)131072 + ((ks - 28) << 9);  // g=1 head
        bn = *(const s8v*)(bp1 + off);
      }
      s8v a0 = *(const s8v*)(XT + (ks << 10) + (lane << 4));
      s8v a1 = *(const s8v*)(XT + 32768 + (ks << 10) + (lane << 4));
      if (ks & 1) {
        accA1 = mfma32(a0, bq1[ks & 3], accA1);
        accB1 = mfma32(a1, bq1[ks & 3], accB1);
      } else {
        accA0 = mfma32(a0, bq1[ks & 3], accA0);
        accB0 = mfma32(a1, bq1[ks & 3], accB0);
      }
      bq1[ks & 3] = bn;
    }
    const float bv1 = b1[gc1];
#pragma unroll
    for (int r = 0; r < 16; ++r) {
      const int rl = (r & 3) + ((r >> 2) << 3) + (lh << 2);
      const int boff = (cb1 + (rl << 4)) ^ m1;
      *(unsigned short*)(H1 + boff) = f2bf(fmaxf(accA0[r] + accA1[r] + bv1, 0.f));
      *(unsigned short*)(H1 + 16384 + boff) = f2bf(fmaxf(accB0[r] + accB1[r] + bv1, 0.f));
    }
    // q2 preload (W2 g=0 ks0..7) + bias
#pragma unroll
    for (int k = 0; k < 8; ++k) q2[k] = *(const s8v*)(bp2 + (k << 9));
    bv2 = b2[gc2];
  }
  __syncthreads();   // H1(0) + WL visible

  // ---- main pipelined loop: iteration g does GEMM2/3(g) + GEMM1(g+1)
  for (int g = 0; g < NG - 1; ++g) {
    const unsigned short* const bp1gn = bp1 + (size_t)(g + 1) * 131072;
    const unsigned short* const bp1gnn = bp1 + (size_t)(g + 2) * 131072;
    const unsigned short* const bp2g = bp2 + ((size_t)g << 15);
    const unsigned short* const bp3g = bp3 + ((size_t)g << 14);
    const bool refill2 = (g + 2 < NG);

    // -------- Phase A: GEMM2(g) + GEMM1(g+1) ks0..15 --------
    f16v acc2a = zf16(), acc2b = zf16();
    f16v accA = zf16(), accB = zf16();
#pragma unroll
    for (int i = 0; i < 16; ++i) {
      s8v a2 = *(const s8v*)(H1 + (mt2 << 14) + (((i << 10) + lb) ^ KM(i)));
      s8v c2 = q2[i & 7];
      if (i < 8) q2[i & 7] = *(const s8v*)(bp2g + ((i + 8) << 9));
      s8v a0 = *(const s8v*)(XT + (i << 10) + (lane << 4));
      s8v a1 = *(const s8v*)(XT + 32768 + (i << 10) + (lane << 4));
      s8v cb = bq1[i & 3];
      bq1[i & 3] = *(const s8v*)(bp1gn + ((i + 4) << 9));
      if (i & 1) acc2b = mfma32(a2, c2, acc2b);
      else       acc2a = mfma32(a2, c2, acc2a);
      accA = mfma32(a0, cb, accA);
      accB = mfma32(a1, cb, accB);
    }
    // b3f preload + H2(g) write
    s8v b3f[8];
#pragma unroll
    for (int k = 0; k < 8; ++k) b3f[k] = *(const s8v*)(bp3g + (k << 9));
    const float bv3 = b3[(g << 7) + gc2];
#pragma unroll
    for (int r = 0; r < 16; ++r) {
      const int rl = (r & 3) + ((r >> 2) << 3) + (lh << 2);
      float v = fmaxf(acc2a[r] + acc2b[r] + bv2, 0.f);
      *(unsigned short*)(H2 + (mt2 << 13) + ((cb2 + (rl << 4)) ^ m2)) = f2bf(v);
    }
    __syncthreads();

    // -------- Phase B: GEMM3(g) + GEMM1(g+1) ks16..31 --------
    f16v acc3a = zf16(), acc3b = zf16();
#pragma unroll
    for (int i = 0; i < 8; ++i) {
      s8v a3 = *(const s8v*)(H2 + (mt2 << 13) + (((i << 10) + lb) ^ KM(i)));
      if (i & 1) acc3b = mfma32(a3, b3f[i], acc3b);
      else       acc3a = mfma32(a3, b3f[i], acc3a);
#pragma unroll
      for (int jj = 0; jj < 2; ++jj) {
        const int k0 = 16 + (i << 1) + jj;
        s8v a0 = *(const s8v*)(XT + (k0 << 10) + (lane << 4));
        s8v a1 = *(const s8v*)(XT + 32768 + (k0 << 10) + (lane << 4));
        s8v cb = bq1[k0 & 3];
        if (k0 + 4 < 32)
          bq1[k0 & 3] = *(const s8v*)(bp1gn + ((k0 + 4) << 9));
        else if (refill2)
          bq1[k0 & 3] = *(const s8v*)(bp1gnn + ((k0 - 28) << 9));
        accA = mfma32(a0, cb, accA);
        accB = mfma32(a1, cb, accB);
      }
    }
#pragma unroll
    for (int r = 0; r < 16; ++r) {
      const int rl = (r & 3) + ((r >> 2) << 3) + (lh << 2);
      racc[r] += WL[((mt2 << 5) + rl) * 20 + g] * (acc3a[r] + acc3b[r] + bv3);
    }
    // H1(g+1) write
    {
      const float bv1n = b1[((g + 1) << 8) + gc1];
#pragma unroll
      for (int r = 0; r < 16; ++r) {
        const int rl = (r & 3) + ((r >> 2) << 3) + (lh << 2);
        const int boff = (cb1 + (rl << 4)) ^ m1;
        *(unsigned short*)(H1 + boff) = f2bf(fmaxf(accA[r] + bv1n, 0.f));
        *(unsigned short*)(H1 + 16384 + boff) = f2bf(fmaxf(accB[r] + bv1n, 0.f));
      }
    }
    // q2 preload for genre g+1 + bias
    {
      const unsigned short* const bp2gn = bp2 + ((size_t)(g + 1) << 15);
#pragma unroll
      for (int k = 0; k < 8; ++k) q2[k] = *(const s8v*)(bp2gn + (k << 9));
      bv2 = b2[((g + 1) << 7) + gc2];
    }
    __syncthreads();
  }

  // ---- tail: GEMM2/3 for last genre (no GEMM1 to pipeline)
  {
    const int g = NG - 1;
    const unsigned short* const bp2g = bp2 + ((size_t)g << 15);
    const unsigned short* const bp3g = bp3 + ((size_t)g << 14);
    f16v acc2a = zf16(), acc2b = zf16();
#pragma unroll
    for (int i = 0; i < 16; ++i) {
      s8v a2 = *(const s8v*)(H1 + (mt2 << 14) + (((i << 10) + lb) ^ KM(i)));
      s8v c2 = q2[i & 7];
      if (i < 8) q2[i & 7] = *(const s8v*)(bp2g + ((i + 8) << 9));
      if (i & 1) acc2b = mfma32(a2, c2, acc2b);
      else       acc2a = mfma32(a2, c2, acc2a);
    }
    s8v b3f[8];
#pragma unroll
    for (int k = 0; k < 8; ++k) b3f[k] = *(const s8v*)(bp3g + (k << 9));
    const float bv3 = b3[(g << 7) + gc2];
#pragma unroll
    for (int r = 0; r < 16; ++r) {
      const int rl = (r & 3) + ((r >> 2) << 3) + (lh << 2);
      float v = fmaxf(acc2a[r] + acc2b[r] + bv2, 0.f);
      *(unsigned short*)(H2 + (mt2 << 13) + ((cb2 + (rl << 4)) ^ m2)) = f2bf(v);
    }
    __syncthreads();

    f16v acc3a = zf16(), acc3b = zf16();
#pragma unroll
    for (int i = 0; i < 8; ++i) {
      s8v a3 = *(const s8v*)(H2 + (mt2 << 13) + (((i << 10) + lb) ^ KM(i)));
      if (i & 1) acc3b = mfma32(a3, b3f[i], acc3b);
      else       acc3a = mfma32(a3, b3f[i], acc3a);
    }
#pragma unroll
    for (int r = 0; r < 16; ++r) {
      const int rl = (r & 3) + ((r >> 2) << 3) + (lh << 2);
      racc[r] += WL[((mt2 << 5) + rl) * 20 + g] * (acc3a[r] + acc3b[r] + bv3);
    }
  }

  // prefetch GEMM4 depth-4 dual queue (flies across the barriers)
  s8v bq4[4][2];
#pragma unroll
  for (int k = 0; k < 4; ++k) {
    bq4[k][0] = *(const s8v*)(bp4a + (k << 9));
    bq4[k][1] = *(const s8v*)(bp4b + (k << 9));
  }
  __syncthreads();  // all GEMM3 H2 reads done
#pragma unroll
  for (int r = 0; r < 16; ++r) {
    const int rl = (r & 3) + ((r >> 2) << 3) + (lh << 2);
    *(unsigned short*)(H2 + (mt2 << 13) + ((cb2 + (rl << 4)) ^ m2)) = f2bf(racc[r]);
  }
  __syncthreads();

  // ---------- GEMM4: out = relu([X | ref] @ Wagg + bagg)  [64,512] ----------
  f16v acc4[2][2];
  acc4[0][0] = zf16(); acc4[0][1] = zf16();
  acc4[1][0] = zf16(); acc4[1][1] = zf16();
#pragma unroll
  for (int ks = 0; ks < 40; ++ks) {
    s8v bn0, bn1;
    if (ks < 36) {
      bn0 = *(const s8v*)(bp4a + ((ks + 4) << 9));
      bn1 = *(const s8v*)(bp4b + ((ks + 4) << 9));
    }
    s8v a0, a1;
    if (ks < 32) {
      a0 = *(const s8v*)(XT + (ks << 10) + (lane << 4));
      a1 = *(const s8v*)(XT + 32768 + (ks << 10) + (lane << 4));
    } else {
      const int hk = ks - 32;
      a0 = *(const s8v*)(H2 + (((hk << 10) + lb) ^ KM(hk)));
      a1 = *(const s8v*)(H2 + 8192 + (((hk << 10) + lb) ^ KM(hk)));
    }
    acc4[0][0] = mfma32(a0, bq4[ks & 3][0], acc4[0][0]);
    acc4[1][0] = mfma32(a1, bq4[ks & 3][0], acc4[1][0]);
    acc4[0][1] = mfma32(a0, bq4[ks & 3][1], acc4[0][1]);
    acc4[1][1] = mfma32(a1, bq4[ks & 3][1], acc4[1][1]);
    if (ks < 36) { bq4[ks & 3][0] = bn0; bq4[ks & 3][1] = bn1; }
  }
  {
    const float bv4a = bagg[(wid << 5) + l31];
    const float bv4b = bagg[((wid + 8) << 5) + l31];
#pragma unroll
    for (int mt = 0; mt < 2; ++mt)
#pragma unroll
      for (int r = 0; r < 16; ++r) {
        const int rl = (r & 3) + ((r >> 2) << 3) + (lh << 2);
        const size_t rbase = (size_t)(row0 + (mt << 5) + rl) << 9;
        out[rbase + (wid << 5) + l31] = fmaxf(acc4[mt][0][r] + bv4a, 0.f);
        out[rbase + ((wid + 8) << 5) + l31] = fmaxf(acc4[mt][1][r] + bv4b, 0.f);
      }
  }
}

// ---------------- workspace layout (bytes) ----------------
#define OFF_W1P   0u          // packed W1   : 4718592
#define OFF_W2P   4718592u    // packed W2   : 1179648
#define OFF_W3P   5898240u    // packed W3   : 589824
#define OFF_W4P   6488064u    // packed Wagg : 655360
#define OFF_WAP   7143424u    // packed Wa   : 32768   (end 7176192)

extern "C" void kernel_launch(void* const* d_in, const int* in_sizes, int n_in,
                              void* d_out, int out_size, void* d_ws, size_t ws_size,
                              hipStream_t stream) {
  const float* X    = (const float*)d_in[0];
  const float* GV   = (const float*)d_in[1];
  const float* W1   = (const float*)d_in[2];
  const float* b1   = (const float*)d_in[3];
  const float* W2   = (const float*)d_in[4];
  const float* b2   = (const float*)d_in[5];
  const float* W3   = (const float*)d_in[6];
  const float* b3   = (const float*)d_in[7];
  const float* Wa   = (const float*)d_in[8];
  const float* ba   = (const float*)d_in[9];
  const float* Wagg = (const float*)d_in[10];
  const float* bagg = (const float*)d_in[11];
  float* out = (float*)d_out;
  char* ws = (char*)d_ws;

  unsigned short* w1p = (unsigned short*)(ws + OFF_W1P);
  unsigned short* w2p = (unsigned short*)(ws + OFF_W2P);
  unsigned short* w3p = (unsigned short*)(ws + OFF_W3P);
  unsigned short* w4p = (unsigned short*)(ws + OFF_W4P);
  unsigned short* wap = (unsigned short*)(ws + OFF_WAP);

  k_pack<<<dim3(64, 18), 256, 0, stream>>>(W1, w1p, 512, 256);
  k_pack<<<dim3(16, 18), 256, 0, stream>>>(W2, w2p, 256, 128);
  k_pack<<<dim3(8, 18), 256, 0, stream>>>(W3, w3p, 128, 128);
  k_pack<<<dim3(160, 1), 256, 0, stream>>>(Wagg, w4p, 640, 512);
  k_packa<<<8, 256, 0, stream>>>(Wa, wap);
  k_main<<<256, 512, 0, stream>>>(X, GV, w1p, w2p, w3p, w4p, wap,
                                  b1, b2, b3, bagg, ba, out);
}

// Round 14
// 159.113 us; speedup vs baseline: 3.4567x; 1.0033x over previous
//
#include <hip/hip_runtime.h>

#define NB 16384
#define ND 512
#define NH 128
#define NHH 256
#define NG 18

typedef short s8v __attribute__((ext_vector_type(8)));
typedef __bf16 bf8v __attribute__((ext_vector_type(8)));
typedef float f16v __attribute__((ext_vector_type(16)));
typedef unsigned int u4v __attribute__((ext_vector_type(4)));

static __device__ __forceinline__ unsigned short f2bf(float f) {
  unsigned int u = __builtin_bit_cast(unsigned int, f);
  u += 0x7FFFu + ((u >> 16) & 1u);
  return (unsigned short)(u >> 16);
}

static __device__ __forceinline__ unsigned pk2(float a, float b) {
  return (unsigned)f2bf(a) | ((unsigned)f2bf(b) << 16);
}

static __device__ __forceinline__ f16v mfma32(s8v a, s8v b, f16v c) {
  return __builtin_amdgcn_mfma_f32_32x32x16_bf16(
      __builtin_bit_cast(bf8v, a), __builtin_bit_cast(bf8v, b), c, 0, 0, 0);
}

static __device__ __forceinline__ f16v zf16() {
  f16v v;
#pragma unroll
  for (int i = 0; i < 16; ++i) v[i] = 0.f;
  return v;
}

// per-ks compile-time swizzle XOR for fragment-linear H1/H2 reads
#define KM(ks) (((((ks) & 1) << 5)) | ((((ks) >> 1) & 1) << 6))

// pack W [G][K][N] f32 -> B-fragment-linear bf16 for mfma_32x32x16
__global__ __launch_bounds__(256) void k_pack(const float* __restrict__ in,
                                              unsigned short* __restrict__ out,
                                              int K, int N) {
  const int g = blockIdx.y;
  const int c = blockIdx.x * 256 + threadIdx.x;
  const int nk = K >> 4;
  const int l = c & 63;
  const int t = c >> 6;
  const int nt = t / nk;
  const int ks = t - nt * nk;
  const int k0 = (ks << 4) + ((l >> 5) << 3);
  const int col = (nt << 5) + (l & 31);
  const float* ip = in + (size_t)g * K * N + (size_t)k0 * N + col;
  u4v pk;
#pragma unroll
  for (int j = 0; j < 4; ++j)
    pk[j] = pk2(ip[(size_t)(2 * j) * N], ip[(size_t)(2 * j + 1) * N]);
  *(u4v*)(out + (size_t)g * K * N + ((size_t)c << 3)) = pk;
}

// pack Wa [512][18] -> fragment stream [32 ks][64 lane][8], cols >= 18 zeroed
__global__ __launch_bounds__(256) void k_packa(const float* __restrict__ wa,
                                               unsigned short* __restrict__ wap) {
  const int t = blockIdx.x * 256 + threadIdx.x;  // 0..2047
  const int ks = t >> 6, l = t & 63;
  const int col = l & 31;
  const int k0 = (ks << 4) + ((l >> 5) << 3);
  u4v pk;
  if (col < 18) {
    const float* ip = wa + (size_t)k0 * NG + col;
#pragma unroll
    for (int j = 0; j < 4; ++j)
      pk[j] = pk2(ip[(size_t)(2 * j) * NG], ip[(size_t)(2 * j + 1) * NG]);
  } else {
    pk[0] = pk[1] = pk[2] = pk[3] = 0u;
  }
  *(u4v*)(wap + ((size_t)t << 3)) = pk;
}

// fused attn + experts + aggregation. 1 block = 64 rows, 8 waves, mfma 32x32x16.
// Cross-genre pipeline + "loads pre-barrier are free" discipline:
//   b2f[16]/b3f[8] fully hoisted before their barriers; GEMM1 queue depth 8.
__global__ __launch_bounds__(512, 1) void k_main(
    const float* __restrict__ X,              // [B][512] f32
    const float* __restrict__ GV,             // [B][18]
    const unsigned short* __restrict__ w1p,   // packed [18][512x256]
    const unsigned short* __restrict__ w2p,   // packed [18][256x128]
    const unsigned short* __restrict__ w3p,   // packed [18][128x128]
    const unsigned short* __restrict__ w4p,   // packed [640x512]
    const unsigned short* __restrict__ wap,   // packed Wa [512x32]
    const float* __restrict__ b1, const float* __restrict__ b2,
    const float* __restrict__ b3, const float* __restrict__ bagg,
    const float* __restrict__ ba,
    float* __restrict__ out) {
  __shared__ __align__(16) char smem[128256];
  char* const XT = smem;                      // [2][32][1024] = 64KB (linear)
  char* const H1 = smem + 65536;              // [2][16][1024] = 32KB (swz)
  char* const H2 = smem + 98304;              // [2][8][1024]  = 16KB (swz)
  float* const WL = (float*)(smem + 114688);  // [64][20] f32 (5120B)
  float* const Lsm = (float*)(smem + 119808); // [64][33] f32 (8448B)

  const int tid = threadIdx.x;
  const int row0 = blockIdx.x << 6;
  const int wid = tid >> 6, lane = tid & 63;
  const int l31 = lane & 31, lh = lane >> 5;
  const int lb = (lane << 4) ^ (lh << 4);     // swizzled read lane-base

  // ---- stage XT (f32 -> bf16) in fragment-linear order
#pragma unroll
  for (int i = 0; i < 8; ++i) {
    int ck = (i << 9) + tid;                  // chunk 0..4095
    int mt = ck >> 11, ks = (ck >> 6) & 31, l = ck & 63;
    int grow = row0 + (mt << 5) + (l & 31);
    int c8 = (ks << 1) + (l >> 5);
    const float* xp = X + ((size_t)grow << 9) + (c8 << 3);
    float4 xa = *(const float4*)xp;
    float4 xc = *(const float4*)(xp + 4);
    u4v p;
    p[0] = pk2(xa.x, xa.y); p[1] = pk2(xa.z, xa.w);
    p[2] = pk2(xc.x, xc.y); p[3] = pk2(xc.z, xc.w);
    *(u4v*)(XT + (ck << 4)) = p;
  }

  // GEMM1 per-wave B base (col-tile = wid); depth-8 queue, g=0 ks0..7
  const unsigned short* const bp1 = w1p + (wid << 14) + (lane << 3);
  s8v bq1[8];
#pragma unroll
  for (int i = 0; i < 8; ++i) bq1[i] = *(const s8v*)(bp1 + (i << 9));

  __syncthreads();

  // ---- attention logits: L = X @ Wa + ba via MFMA (waves 0,1)
  if (wid < 2) {
    f16v accL = zf16();
    const unsigned short* const bpa = wap + (lane << 3);
#pragma unroll
    for (int ks = 0; ks < 32; ++ks) {
      s8v a = *(const s8v*)(XT + (wid << 15) + (ks << 10) + (lane << 4));
      s8v b = *(const s8v*)(bpa + (ks << 9));
      accL = mfma32(a, b, accL);
    }
    const float bav = (l31 < NG) ? ba[l31] : 0.f;
#pragma unroll
    for (int r = 0; r < 16; ++r) {
      const int rl = (r & 3) + ((r >> 2) << 3) + (lh << 2);
      Lsm[((wid << 5) + rl) * 33 + l31] = accL[r] + bav;
    }
  }
  __syncthreads();

  // ---- softmax * genre mask -> WL (8 lanes per wave, one row each)
  if (lane < 8) {
    const int row = (wid << 3) + lane;
    float lg[NG], mx = -3.4e38f;
#pragma unroll
    for (int q = 0; q < NG; ++q) { lg[q] = Lsm[row * 33 + q]; mx = fmaxf(mx, lg[q]); }
    float s = 0.f;
#pragma unroll
    for (int q = 0; q < NG; ++q) { lg[q] = expf(lg[q] - mx); s += lg[q]; }
    const float inv = 1.f / s;
#pragma unroll
    for (int q = 0; q < NG; ++q) {
      float gv = GV[(size_t)(row0 + row) * NG + q];
      WL[row * 20 + q] = gv > 0.f ? lg[q] * inv * gv : 0.f;
    }
  }

  // ---- wave tile assignment
  const int nt2 = wid & 3, mt2 = wid >> 2;    // GEMM2/3 tile
  const unsigned short* const bp2 = w2p + (nt2 << 13) + (lane << 3);
  const unsigned short* const bp3 = w3p + (nt2 << 12) + (lane << 3);
  const unsigned short* const bp4a = w4p + (size_t)wid * 20480 + (lane << 3);
  const unsigned short* const bp4b = w4p + (size_t)(wid + 8) * 20480 + (lane << 3);

  // per-lane swizzled write bases (genre-invariant)
  const int gc1 = (wid << 5) + l31;           // GEMM1 col
  const int gc2 = (nt2 << 5) + l31;           // GEMM2/3 col
  const int cb1 = ((gc1 >> 4) << 10) + (((gc1 >> 3) & 1) << 9) + ((gc1 & 7) << 1);
  const int cb2 = ((gc2 >> 4) << 10) + (((gc2 >> 3) & 1) << 9) + ((gc2 & 7) << 1);
  const int m1 = (((cb1 >> 9) & 1) << 4) | (((cb1 >> 10) & 1) << 5) | (((cb1 >> 11) & 1) << 6);
  const int m2 = (((cb2 >> 9) & 1) << 4) | (((cb2 >> 10) & 1) << 5) | (((cb2 >> 11) & 1) << 6);

  f16v racc = zf16();
  s8v b2f[16];
  float bv2;

  // ---- prologue: GEMM1(0) full (not pipelined), depth-8 queue
  {
    f16v accA0 = zf16(), accA1 = zf16(), accB0 = zf16(), accB1 = zf16();
#pragma unroll
    for (int ks = 0; ks < 32; ++ks) {
      s8v bn;
      {
        size_t off = (ks < 24) ? (size_t)((ks + 8) << 9)
                               : (size_t)131072 + ((ks - 24) << 9);  // g=1 frags 0..7
        bn = *(const s8v*)(bp1 + off);
      }
      s8v a0 = *(const s8v*)(XT + (ks << 10) + (lane << 4));
      s8v a1 = *(const s8v*)(XT + 32768 + (ks << 10) + (lane << 4));
      if (ks & 1) {
        accA1 = mfma32(a0, bq1[ks & 7], accA1);
        accB1 = mfma32(a1, bq1[ks & 7], accB1);
      } else {
        accA0 = mfma32(a0, bq1[ks & 7], accA0);
        accB0 = mfma32(a1, bq1[ks & 7], accB0);
      }
      bq1[ks & 7] = bn;
    }
    const float bv1 = b1[gc1];
#pragma unroll
    for (int r = 0; r < 16; ++r) {
      const int rl = (r & 3) + ((r >> 2) << 3) + (lh << 2);
      const int boff = (cb1 + (rl << 4)) ^ m1;
      *(unsigned short*)(H1 + boff) = f2bf(fmaxf(accA0[r] + accA1[r] + bv1, 0.f));
      *(unsigned short*)(H1 + 16384 + boff) = f2bf(fmaxf(accB0[r] + accB1[r] + bv1, 0.f));
    }
    // b2f full preload (W2 g=0) + bias — completes inside the barrier drain
#pragma unroll
    for (int k = 0; k < 16; ++k) b2f[k] = *(const s8v*)(bp2 + (k << 9));
    bv2 = b2[gc2];
  }
  __syncthreads();   // H1(0) + WL visible; b2f ready

  // ---- main pipelined loop: iteration g does GEMM2/3(g) + GEMM1(g+1)
  for (int g = 0; g < NG - 1; ++g) {
    const unsigned short* const bp1gn = bp1 + (size_t)(g + 1) * 131072;
    const unsigned short* const bp1gnn = bp1 + (size_t)(g + 2) * 131072;
    const unsigned short* const bp3g = bp3 + ((size_t)g << 14);
    const bool refill2 = (g + 2 < NG);

    // -------- Phase A: GEMM2(g) + GEMM1(g+1) ks0..15 --------
    f16v acc2a = zf16(), acc2b = zf16();
    f16v accA = zf16(), accB = zf16();
#pragma unroll
    for (int i = 0; i < 16; ++i) {
      s8v a2 = *(const s8v*)(H1 + (mt2 << 14) + (((i << 10) + lb) ^ KM(i)));
      s8v a0 = *(const s8v*)(XT + (i << 10) + (lane << 4));
      s8v a1 = *(const s8v*)(XT + 32768 + (i << 10) + (lane << 4));
      s8v cb = bq1[i & 7];
      bq1[i & 7] = *(const s8v*)(bp1gn + ((i + 8) << 9));
      if (i & 1) acc2b = mfma32(a2, b2f[i], acc2b);
      else       acc2a = mfma32(a2, b2f[i], acc2a);
      accA = mfma32(a0, cb, accA);
      accB = mfma32(a1, cb, accB);
    }
    // b3f preload + H2(g) write (loads complete inside the barrier drain)
    s8v b3f[8];
#pragma unroll
    for (int k = 0; k < 8; ++k) b3f[k] = *(const s8v*)(bp3g + (k << 9));
    const float bv3 = b3[(g << 7) + gc2];
#pragma unroll
    for (int r = 0; r < 16; ++r) {
      const int rl = (r & 3) + ((r >> 2) << 3) + (lh << 2);
      float v = fmaxf(acc2a[r] + acc2b[r] + bv2, 0.f);
      *(unsigned short*)(H2 + (mt2 << 13) + ((cb2 + (rl << 4)) ^ m2)) = f2bf(v);
    }
    __syncthreads();

    // -------- Phase B: GEMM3(g) + GEMM1(g+1) ks16..31 --------
    f16v acc3a = zf16(), acc3b = zf16();
#pragma unroll
    for (int i = 0; i < 8; ++i) {
      s8v a3 = *(const s8v*)(H2 + (mt2 << 13) + (((i << 10) + lb) ^ KM(i)));
      if (i & 1) acc3b = mfma32(a3, b3f[i], acc3b);
      else       acc3a = mfma32(a3, b3f[i], acc3a);
#pragma unroll
      for (int jj = 0; jj < 2; ++jj) {
        const int k0 = 16 + (i << 1) + jj;
        s8v a0 = *(const s8v*)(XT + (k0 << 10) + (lane << 4));
        s8v a1 = *(const s8v*)(XT + 32768 + (k0 << 10) + (lane << 4));
        s8v cb = bq1[k0 & 7];
        if (k0 + 8 < 32)
          bq1[k0 & 7] = *(const s8v*)(bp1gn + ((k0 + 8) << 9));
        else if (refill2)
          bq1[k0 & 7] = *(const s8v*)(bp1gnn + ((k0 - 24) << 9));
        accA = mfma32(a0, cb, accA);
        accB = mfma32(a1, cb, accB);
      }
    }
#pragma unroll
    for (int r = 0; r < 16; ++r) {
      const int rl = (r & 3) + ((r >> 2) << 3) + (lh << 2);
      racc[r] += WL[((mt2 << 5) + rl) * 20 + g] * (acc3a[r] + acc3b[r] + bv3);
    }
    // H1(g+1) write
    {
      const float bv1n = b1[((g + 1) << 8) + gc1];
#pragma unroll
      for (int r = 0; r < 16; ++r) {
        const int rl = (r & 3) + ((r >> 2) << 3) + (lh << 2);
        const int boff = (cb1 + (rl << 4)) ^ m1;
        *(unsigned short*)(H1 + boff) = f2bf(fmaxf(accA[r] + bv1n, 0.f));
        *(unsigned short*)(H1 + 16384 + boff) = f2bf(fmaxf(accB[r] + bv1n, 0.f));
      }
    }
    // b2f full preload for genre g+1 + bias (free under the barrier drain)
    {
      const unsigned short* const bp2gn = bp2 + ((size_t)(g + 1) << 15);
#pragma unroll
      for (int k = 0; k < 16; ++k) b2f[k] = *(const s8v*)(bp2gn + (k << 9));
      bv2 = b2[((g + 1) << 7) + gc2];
    }
    __syncthreads();
  }

  // ---- tail: GEMM2/3 for last genre (no GEMM1 to pipeline)
  {
    const int g = NG - 1;
    const unsigned short* const bp3g = bp3 + ((size_t)g << 14);
    f16v acc2a = zf16(), acc2b = zf16();
#pragma unroll
    for (int i = 0; i < 16; ++i) {
      s8v a2 = *(const s8v*)(H1 + (mt2 << 14) + (((i << 10) + lb) ^ KM(i)));
      if (i & 1) acc2b = mfma32(a2, b2f[i], acc2b);
      else       acc2a = mfma32(a2, b2f[i], acc2a);
    }
    s8v b3f[8];
#pragma unroll
    for (int k = 0; k < 8; ++k) b3f[k] = *(const s8v*)(bp3g + (k << 9));
    const float bv3 = b3[(g << 7) + gc2];
#pragma unroll
    for (int r = 0; r < 16; ++r) {
      const int rl = (r & 3) + ((r >> 2) << 3) + (lh << 2);
      float v = fmaxf(acc2a[r] + acc2b[r] + bv2, 0.f);
      *(unsigned short*)(H2 + (mt2 << 13) + ((cb2 + (rl << 4)) ^ m2)) = f2bf(v);
    }
    __syncthreads();

    f16v acc3a = zf16(), acc3b = zf16();
#pragma unroll
    for (int i = 0; i < 8; ++i) {
      s8v a3 = *(const s8v*)(H2 + (mt2 << 13) + (((i << 10) + lb) ^ KM(i)));
      if (i & 1) acc3b = mfma32(a3, b3f[i], acc3b);
      else       acc3a = mfma32(a3, b3f[i], acc3a);
    }
#pragma unroll
    for (int r = 0; r < 16; ++r) {
      const int rl = (r & 3) + ((r >> 2) << 3) + (lh << 2);
      racc[r] += WL[((mt2 << 5) + rl) * 20 + g] * (acc3a[r] + acc3b[r] + bv3);
    }
  }

  // prefetch GEMM4 depth-4 dual queue (flies across the barriers)
  s8v bq4[4][2];
#pragma unroll
  for (int k = 0; k < 4; ++k) {
    bq4[k][0] = *(const s8v*)(bp4a + (k << 9));
    bq4[k][1] = *(const s8v*)(bp4b + (k << 9));
  }
  __syncthreads();  // all GEMM3 H2 reads done
#pragma unroll
  for (int r = 0; r < 16; ++r) {
    const int rl = (r & 3) + ((r >> 2) << 3) + (lh << 2);
    *(unsigned short*)(H2 + (mt2 << 13) + ((cb2 + (rl << 4)) ^ m2)) = f2bf(racc[r]);
  }
  __syncthreads();

  // ---------- GEMM4: out = relu([X | ref] @ Wagg + bagg)  [64,512] ----------
  f16v acc4[2][2];
  acc4[0][0] = zf16(); acc4[0][1] = zf16();
  acc4[1][0] = zf16(); acc4[1][1] = zf16();
#pragma unroll
  for (int ks = 0; ks < 40; ++ks) {
    s8v bn0, bn1;
    if (ks < 36) {
      bn0 = *(const s8v*)(bp4a + ((ks + 4) << 9));
      bn1 = *(const s8v*)(bp4b + ((ks + 4) << 9));
    }
    s8v a0, a1;
    if (ks < 32) {
      a0 = *(const s8v*)(XT + (ks << 10) + (lane << 4));
      a1 = *(const s8v*)(XT + 32768 + (ks << 10) + (lane << 4));
    } else {
      const int hk = ks - 32;
      a0 = *(const s8v*)(H2 + (((hk << 10) + lb) ^ KM(hk)));
      a1 = *(const s8v*)(H2 + 8192 + (((hk << 10) + lb) ^ KM(hk)));
    }
    acc4[0][0] = mfma32(a0, bq4[ks & 3][0], acc4[0][0]);
    acc4[1][0] = mfma32(a1, bq4[ks & 3][0], acc4[1][0]);
    acc4[0][1] = mfma32(a0, bq4[ks & 3][1], acc4[0][1]);
    acc4[1][1] = mfma32(a1, bq4[ks & 3][1], acc4[1][1]);
    if (ks < 36) { bq4[ks & 3][0] = bn0; bq4[ks & 3][1] = bn1; }
  }
  {
    const float bv4a = bagg[(wid << 5) + l31];
    const float bv4b = bagg[((wid + 8) << 5) + l31];
#pragma unroll
    for (int mt = 0; mt < 2; ++mt)
#pragma unroll
      for (int r = 0; r < 16; ++r) {
        const int rl = (r & 3) + ((r >> 2) << 3) + (lh << 2);
        const size_t rbase = (size_t)(row0 + (mt << 5) + rl) << 9;
        out[rbase + (wid << 5) + l31] = fmaxf(acc4[mt][0][r] + bv4a, 0.f);
        out[rbase + ((wid + 8) << 5) + l31] = fmaxf(acc4[mt][1][r] + bv4b, 0.f);
      }
  }
}

// ---------------- workspace layout (bytes) ----------------
#define OFF_W1P   0u          // packed W1   : 4718592
#define OFF_W2P   4718592u    // packed W2   : 1179648
#define OFF_W3P   5898240u    // packed W3   : 589824
#define OFF_W4P   6488064u    // packed Wagg : 655360
#define OFF_WAP   7143424u    // packed Wa   : 32768   (end 7176192)

extern "C" void kernel_launch(void* const* d_in, const int* in_sizes, int n_in,
                              void* d_out, int out_size, void* d_ws, size_t ws_size,
                              hipStream_t stream) {
  const float* X    = (const float*)d_in[0];
  const float* GV   = (const float*)d_in[1];
  const float* W1   = (const float*)d_in[2];
  const float* b1   = (const float*)d_in[3];
  const float* W2   = (const float*)d_in[4];
  const float* b2   = (const float*)d_in[5];
  const float* W3   = (const float*)d_in[6];
  const float* b3   = (const float*)d_in[7];
  const float* Wa   = (const float*)d_in[8];
  const float* ba   = (const float*)d_in[9];
  const float* Wagg = (const float*)d_in[10];
  const float* bagg = (const float*)d_in[11];
  float* out = (float*)d_out;
  char* ws = (char*)d_ws;

  unsigned short* w1p = (unsigned short*)(ws + OFF_W1P);
  unsigned short* w2p = (unsigned short*)(ws + OFF_W2P);
  unsigned short* w3p = (unsigned short*)(ws + OFF_W3P);
  unsigned short* w4p = (unsigned short*)(ws + OFF_W4P);
  unsigned short* wap = (unsigned short*)(ws + OFF_WAP);

  k_pack<<<dim3(64, 18), 256, 0, stream>>>(W1, w1p, 512, 256);
  k_pack<<<dim3(16, 18), 256, 0, stream>>>(W2, w2p, 256, 128);
  k_pack<<<dim3(8, 18), 256, 0, stream>>>(W3, w3p, 128, 128);
  k_pack<<<dim3(160, 1), 256, 0, stream>>>(Wagg, w4p, 640, 512);
  k_packa<<<8, 256, 0, stream>>>(Wa, wap);
  k_main<<<256, 512, 0, stream>>>(X, GV, w1p, w2p, w3p, w4p, wap,
                                  b1, b2, b3, bagg, ba, out);
}